// Round 11
// baseline (935.992 us; speedup 1.0000x reference)
//
#include <hip/hip_runtime.h>

// GraphSAGE-pool ×3 + BN + classifier, bf16 activations + MFMA GEMMs.
// R11 = R10 + column-sliced aggregation for L2 residency:
//   hp and agg stored as 8 col-slices of 16 cols (3.2 MB/slice < 4 MB XCD L2).
//   Aggregate pass s runs on blockIdx&7==s (XCD s): random gathers hit the
//   XCD's own L2 instead of L3 (R10 aggregate: 113 MB L2-miss @ 2.5 TB/s).
//   One wave-load covers 8 edges x 32 B; shfl-reduce across edge groups.
//   gemm<4>: sliced-out epilogue (hp); gemm<8>: sliced A2 stage (agg).

#define N_NODES 100000
#define N_EDGES 1000000
#define F 128
#define NEG_SLOPE 0.01f
#define BN_EPS 1e-5f
#define NODES_PER_XCD 12500
#define SLICE_STRIDE ((size_t)N_NODES * 16)   // shorts per 16-col slice

typedef __attribute__((ext_vector_type(8))) short bf16x8;
typedef __attribute__((ext_vector_type(4))) float f32x4;

typedef __attribute__((address_space(3))) unsigned int as3_uint;
typedef __attribute__((address_space(1))) const unsigned int as1_cuint;

__device__ __forceinline__ void gload16(const void* g, void* l) {
    __builtin_amdgcn_global_load_lds((as1_cuint*)g, (as3_uint*)l, 16, 0, 0);
}

__device__ __forceinline__ unsigned short f2bf(float f) {
    unsigned int u = __float_as_uint(f);
    u += 0x7fff + ((u >> 16) & 1);          // RNE
    return (unsigned short)(u >> 16);
}
__device__ __forceinline__ float bf2f(unsigned short h) {
    return __uint_as_float(((unsigned int)h) << 16);
}

// ---------------- zero fill ----------------
__global__ __launch_bounds__(256) void zero_kernel(float4* __restrict__ p, long n4) {
    long i = (long)blockIdx.x * 256 + threadIdx.x;
    if (i < n4) p[i] = make_float4(0.f, 0.f, 0.f, 0.f);
}

// ---------------- fp32 -> bf16 convert ----------------
__global__ __launch_bounds__(256) void f32_to_bf16_kernel(
    const float4* __restrict__ in, uint2* __restrict__ out, long n4)
{
    long i = (long)blockIdx.x * 256 + threadIdx.x;
    if (i >= n4) return;
    float4 v = in[i];
    uint2 o;
    o.x = (unsigned)f2bf(v.x) | ((unsigned)f2bf(v.y) << 16);
    o.y = (unsigned)f2bf(v.z) | ((unsigned)f2bf(v.w) << 16);
    out[i] = o;
}

// ---------------- weight pack: f32 [128][128] -> bf16 frag-order [16][128][8] ----------------
__global__ __launch_bounds__(256) void pack_weights3(
    const float* __restrict__ wp, const float* __restrict__ wss,
    const float* __restrict__ wn, short* __restrict__ wp_p, short* __restrict__ wsn_p)
{
    const int i = blockIdx.x * 256 + threadIdx.x;   // 0..49151
    if (i >= 3 * 16384) return;
    const int mat = i >> 14;
    const int idx = i & 16383;
    const int k = idx >> 7, n = idx & 127;
    const float* srcm = mat == 0 ? wp : (mat == 1 ? wss : wn);
    const int slot = ((k >> 3) * 128 + n) * 8 + (k & 7);
    if (mat == 0) wp_p[slot] = (short)f2bf(srcm[idx]);
    else wsn_p[(mat == 2 ? 16 * 128 * 8 : 0) + slot] = (short)f2bf(srcm[idx]);
}

// ---------------- MFMA GEMM, m97-style; optional sliced output / sliced A2 ----------------
// Sliced layout: element (row, col) -> slice (col/16) at [row*16 + col%16] shorts.
template<int NKS, bool SLICED_OUT, bool SLICED_A2>
__global__ __launch_bounds__(256) void gemm_mfma(
    const short* __restrict__ A1, const short* __restrict__ A2,
    const short* __restrict__ Bp, const float* __restrict__ bias,
    unsigned short* __restrict__ Cout, int n_rows, int act)
{
    constexpr int S = NKS / 2;                   // BK=64 steps
    __shared__ short tile[2 * 8192];             // 2 x (128 rows x 64 cols); reused as epilogue bounce

    const int tid = threadIdx.x;
    const int wave = tid >> 6;
    const int lane = tid & 63;
    const int m = lane & 15, q = lane >> 4;
    const int r0 = blockIdx.x * 128;
    const int rw = (wave >> 1) * 64;             // wave row-quadrant offset
    const int r0q = r0 + rw;
    const int c0 = (wave & 1) * 64;
    const int gchunk = (tid & 7) ^ ((tid >> 3) & 7);

    f32x4 acc[4][4];
#pragma unroll
    for (int i = 0; i < 4; ++i)
#pragma unroll
        for (int j = 0; j < 4; ++j)
#pragma unroll
            for (int r = 0; r < 4; ++r) acc[i][j][r] = 0.f;

    auto stage = [&](int s, int buf) {
        const int kbase = (s & 1) * 64;          // shorts
#pragma unroll
        for (int p = 0; p < 4; ++p) {
            int row = r0 + (tid >> 3) + 32 * p;
            row = min(row, n_rows - 1);
            const short* gp;
            if (NKS == 8 && s >= 2) {
                if (SLICED_A2) {
                    const int cg = (s & 1) * 8 + gchunk;   // 16B chunk 0..15 within A2
                    gp = A2 + (size_t)(cg >> 1) * SLICE_STRIDE + (size_t)row * 16 + (cg & 1) * 8;
                } else {
                    gp = A2 + (size_t)row * F + kbase + gchunk * 8;
                }
            } else {
                gp = A1 + (size_t)row * F + kbase + gchunk * 8;
            }
            gload16(gp, &tile[buf * 8192 + p * 2048 + tid * 8]);
        }
    };

    stage(0, 0);
    __syncthreads();

    for (int s = 0; s < S; ++s) {
        if (s + 1 < S) stage(s + 1, (s + 1) & 1);
        const short* tb = &tile[(s & 1) * 8192];
#pragma unroll
        for (int ks2 = 0; ks2 < 2; ++ks2) {
            const int ks32 = s * 2 + ks2;
            bf16x8 b[4], a[4];
#pragma unroll
            for (int ni = 0; ni < 4; ++ni)
                b[ni] = *(const bf16x8*)(Bp + ((size_t)(ks32 * 4 + q) * F + c0 + ni * 16 + m) * 8);
#pragma unroll
            for (int mi = 0; mi < 4; ++mi)
                a[mi] = *(const bf16x8*)(tb + (rw + mi * 16 + m) * 64 + (((ks2 * 4 + q) ^ (m & 7)) << 3));
#pragma unroll
            for (int mi = 0; mi < 4; ++mi)
#pragma unroll
                for (int ni = 0; ni < 4; ++ni)
                    acc[mi][ni] = __builtin_amdgcn_mfma_f32_16x16x32_bf16(a[mi], b[ni], acc[mi][ni], 0, 0, 0);
        }
        __syncthreads();   // after last step: all reads of tile done -> safe to alias
    }

    float bv[4];
#pragma unroll
    for (int ni = 0; ni < 4; ++ni) bv[ni] = bias[c0 + ni * 16 + m];

    short* ep = &tile[wave * 1280];              // aliased onto dead A-tile buffer
    const int colc_lo = m >> 3, cin = m & 7;
#pragma unroll
    for (int mi = 0; mi < 4; ++mi) {
#pragma unroll
        for (int ni = 0; ni < 4; ++ni) {
            const int colc = 2 * ni + colc_lo;
#pragma unroll
            for (int rg = 0; rg < 4; ++rg) {
                const int row16 = q * 4 + rg;
                float v = acc[mi][ni][rg] + bv[ni];
                if (act == 1) v = v > 0.f ? v : 0.f;
                else if (act == 2) v = v > 0.f ? v : v * NEG_SLOPE;
                ep[row16 * 80 + ((colc ^ (row16 & 7)) << 3) + cin] = (short)f2bf(v);
            }
        }
        __syncthreads();
#pragma unroll
        for (int p = 0; p < 2; ++p) {
            const int lrow = (lane >> 3) + 8 * p;
            bf16x8 vv = *(const bf16x8*)&ep[lrow * 80 + (((lane & 7) ^ (lrow & 7)) << 3)];
            const int grow = r0q + mi * 16 + lrow;
            if (grow < n_rows) {
                if (SLICED_OUT) {
                    const int cg = (c0 >> 3) + (lane & 7);    // 16B chunk 0..15
                    *(bf16x8*)(Cout + (size_t)(cg >> 1) * SLICE_STRIDE + (size_t)grow * 16 + (cg & 1) * 8) = vv;
                } else {
                    *(bf16x8*)(Cout + (size_t)grow * F + c0 + ((lane & 7) << 3)) = vv;
                }
            }
        }
        __syncthreads();
    }
}

// ---------------- CSR build (R10-verified) ----------------
__global__ __launch_bounds__(256) void hist_kernel(const int* __restrict__ dst, int* __restrict__ deg) {
    const int e = blockIdx.x * 256 + threadIdx.x;
    if (e < N_EDGES) atomicAdd(&deg[__builtin_nontemporal_load(&dst[e])], 1);
}

__global__ __launch_bounds__(256) void scan1_kernel(const int* __restrict__ deg, int* __restrict__ bsum) {
    __shared__ int sh[256];
    const int t = threadIdx.x;
    const int base = blockIdx.x * 1024 + t * 4;
    int s = 0;
#pragma unroll
    for (int j = 0; j < 4; ++j) s += (base + j < N_NODES) ? deg[base + j] : 0;
    sh[t] = s; __syncthreads();
    for (int off = 128; off; off >>= 1) {
        if (t < off) sh[t] += sh[t + off];
        __syncthreads();
    }
    if (t == 0) bsum[blockIdx.x] = sh[0];
}

__global__ __launch_bounds__(128) void scan2_kernel(int* __restrict__ bsum, int nb, int* __restrict__ row_start) {
    __shared__ int sh[128];
    const int t = threadIdx.x;
    sh[t] = (t < nb) ? bsum[t] : 0;
    __syncthreads();
    for (int off = 1; off < 128; off <<= 1) {
        int x = (t >= off) ? sh[t - off] : 0;
        __syncthreads();
        if (t >= off) sh[t] += x;
        __syncthreads();
    }
    if (t < nb) bsum[t] = t ? sh[t - 1] : 0;
    if (t == 0) row_start[N_NODES] = N_EDGES;
}

__global__ __launch_bounds__(256) void scan3_kernel(
    const int* __restrict__ deg, const int* __restrict__ boff,
    int* __restrict__ row_start, int* __restrict__ cursor)
{
    __shared__ int sh[256];
    const int t = threadIdx.x;
    const int base = blockIdx.x * 1024 + t * 4;
    int v[4]; int s = 0;
#pragma unroll
    for (int j = 0; j < 4; ++j) { v[j] = (base + j < N_NODES) ? deg[base + j] : 0; s += v[j]; }
    sh[t] = s; __syncthreads();
    for (int off = 1; off < 256; off <<= 1) {
        int x = (t >= off) ? sh[t - off] : 0;
        __syncthreads();
        if (t >= off) sh[t] += x;
        __syncthreads();
    }
    int excl = (t ? sh[t - 1] : 0) + boff[blockIdx.x];
#pragma unroll
    for (int j = 0; j < 4; ++j) {
        if (base + j < N_NODES) { row_start[base + j] = excl; cursor[base + j] = excl; }
        excl += v[j];
    }
}

#define CHUNK_E2 1954
__global__ __launch_bounds__(256) void scatter_xcd_kernel(
    const int* __restrict__ src, const int* __restrict__ dst,
    int* __restrict__ cursor, int* __restrict__ esrc)
{
    const int range = blockIdx.x & 7;
    const int chunk = blockIdx.x >> 3;            // 0..511
    const int lo = range * NODES_PER_XCD;
    const int e0 = chunk * CHUNK_E2;
    const int e1 = min(e0 + CHUNK_E2, N_EDGES);
    for (int e = e0 + threadIdx.x; e < e1; e += 256) {
        const int d = dst[e];
        if ((unsigned)(d - lo) < NODES_PER_XCD) {
            const int pos = atomicAdd(&cursor[d], 1);
            esrc[pos] = src[e];
        }
    }
}

// ---------------- sliced aggregation ----------------
// blockIdx&7 = col-slice s (-> XCD s; its 3.2 MB hp slice is L2-resident).
// Wave handles one node; lane = (edge-group 0..7) x (col-pair 0..7): one
// wave-load covers 8 edges x 32 B. shfl-reduce over edge groups; lanes 0..7
// write the node's 32 B agg chunk. Init 0 == post-relu max + deg-mask.
__global__ __launch_bounds__(256) void aggregate_max_sliced(
    const unsigned short* __restrict__ hpS, const int* __restrict__ row_start,
    const int* __restrict__ esrc, unsigned short* __restrict__ aggS)
{
    const int s = blockIdx.x & 7;
    const int node = (blockIdx.x >> 3) * 4 + (threadIdx.x >> 6);
    if (node >= N_NODES) return;
    const int lane = threadIdx.x & 63;
    const int e8 = lane >> 3, cp = lane & 7;
    const unsigned short* hps = hpS + (size_t)s * SLICE_STRIDE;
    const int beg = row_start[node], end = row_start[node + 1];
    unsigned int m0 = 0, m1 = 0;
    for (int i = beg + e8; i < end; i += 8) {
        const int sn = esrc[i];
        const unsigned int v = *(const unsigned int*)(hps + (size_t)sn * 16 + cp * 2);
        m0 = max(m0, v & 0xffffu);
        m1 = max(m1, v >> 16);
    }
#pragma unroll
    for (int off = 32; off >= 8; off >>= 1) {
        m0 = max(m0, (unsigned int)__shfl_down((int)m0, off));
        m1 = max(m1, (unsigned int)__shfl_down((int)m1, off));
    }
    if (lane < 8)
        *(unsigned int*)(aggS + (size_t)s * SLICE_STRIDE + (size_t)node * 16 + lane * 2)
            = m0 | (m1 << 16);
}

// ---------------- BN stats (verified R8) ----------------
#define BN_ROWS_PER_BLOCK 196
__global__ __launch_bounds__(256) void bn_stats_kernel(
    const unsigned short* __restrict__ x, float* __restrict__ stats, int n)
{
    const int tid = threadIdx.x;
    const int wave = tid >> 6, lane = tid & 63;
    const int rgrp = lane >> 4;
    const int c16 = lane & 15;
    const int rbase = blockIdx.x * BN_ROWS_PER_BLOCK;
    const int rend = min(rbase + BN_ROWS_PER_BLOCK, n);

    float s[8], ss[8];
#pragma unroll
    for (int j = 0; j < 8; ++j) { s[j] = 0.f; ss[j] = 0.f; }

    for (int r = rbase + wave * 4 + rgrp; r < rend; r += 16) {
        const uint4 v = *(const uint4*)(x + (size_t)r * F + c16 * 8);
        const unsigned int w[4] = {v.x, v.y, v.z, v.w};
#pragma unroll
        for (int u = 0; u < 4; ++u) {
            const float f0 = bf2f((unsigned short)(w[u] & 0xffffu));
            const float f1 = bf2f((unsigned short)(w[u] >> 16));
            s[2*u]   += f0; ss[2*u]   = fmaf(f0, f0, ss[2*u]);
            s[2*u+1] += f1; ss[2*u+1] = fmaf(f1, f1, ss[2*u+1]);
        }
    }
#pragma unroll
    for (int j = 0; j < 8; ++j) {
        s[j]  += __shfl_down(s[j], 32);  s[j]  += __shfl_down(s[j], 16);
        ss[j] += __shfl_down(ss[j], 32); ss[j] += __shfl_down(ss[j], 16);
    }
    __shared__ float sh[4][16][16];
    if (lane < 16) {
#pragma unroll
        for (int j = 0; j < 8; ++j) {
            sh[wave][c16][2*j]     = s[j];
            sh[wave][c16][2*j + 1] = ss[j];
        }
    }
    __syncthreads();
    const float tot = sh[0][tid >> 4][tid & 15] + sh[1][tid >> 4][tid & 15]
                    + sh[2][tid >> 4][tid & 15] + sh[3][tid >> 4][tid & 15];
    const int col = (tid >> 4) * 8 + ((tid >> 1) & 7);
    atomicAdd(&stats[(tid & 1) * 128 + col], tot);
}

__global__ void bn_finalize_kernel(
    const float* __restrict__ stats, const float* __restrict__ gamma,
    const float* __restrict__ beta, float* __restrict__ coef)
{
    const int c = threadIdx.x;
    const float mean = stats[c] * (1.f / N_NODES);
    const float var = stats[128 + c] * (1.f / N_NODES) - mean * mean;
    const float scale = gamma[c] * rsqrtf(var + BN_EPS);
    coef[c] = scale;
    coef[128 + c] = fmaf(-mean, scale, beta[c]);
}

__global__ __launch_bounds__(256) void bn_apply_bf16(
    unsigned int* __restrict__ x, const float* __restrict__ coef, long n2)
{
    __shared__ float sc[128], sf[128];
    if (threadIdx.x < 128) {
        sc[threadIdx.x] = coef[threadIdx.x];
        sf[threadIdx.x] = coef[128 + threadIdx.x];
    }
    __syncthreads();
    const long i = (long)blockIdx.x * 256 + threadIdx.x;
    if (i >= n2) return;
    const unsigned int v = x[i];
    const int c0 = (int)(i & 63) * 2;
    float a = fmaf(bf2f((unsigned short)(v & 0xffffu)), sc[c0], sf[c0]);
    float b = fmaf(bf2f((unsigned short)(v >> 16)), sc[c0 + 1], sf[c0 + 1]);
    a = a > 0.f ? a : a * NEG_SLOPE;
    b = b > 0.f ? b : b * NEG_SLOPE;
    x[i] = (unsigned)f2bf(a) | ((unsigned)f2bf(b) << 16);
}

// ---------------- classifier ----------------
__global__ __launch_bounds__(256) void classifier_kernel(
    const unsigned short* __restrict__ X, const float* __restrict__ Wc,
    const float* __restrict__ bc, float* __restrict__ out, int n)
{
    __shared__ float Wl[2048];
    __shared__ float Xs[16 * 132];
    const int tid = threadIdx.x;
    for (int i = tid; i < 2048; i += 256) Wl[i] = Wc[i];
    const int r0 = blockIdx.x * 16;
    for (int i = tid; i < 2048; i += 256) {
        const int row = i >> 7, col = i & 127;
        const int gr = r0 + row;
        Xs[row * 132 + col] = (gr < n) ? bf2f(X[(size_t)gr * F + col]) : 0.f;
    }
    __syncthreads();
    const int rl = tid >> 4, c = tid & 15;
    const int r = r0 + rl;
    if (r >= n) return;
    float s = bc[c];
    const float* xr = &Xs[rl * 132];
#pragma unroll
    for (int k = 0; k < 128; ++k) s = fmaf(xr[k], Wl[k * 16 + c], s);
    out[(size_t)r * 16 + c] = s;
}

extern "C" void kernel_launch(void* const* d_in, const int* in_sizes, int n_in,
                              void* d_out, int out_size, void* d_ws, size_t ws_size,
                              hipStream_t stream) {
    const float* node_feat = (const float*)d_in[0];
    const int* src = (const int*)d_in[1];
    const int* dst = (const int*)d_in[2];
    const float* wp[3] = {(const float*)d_in[3],  (const float*)d_in[8],  (const float*)d_in[13]};
    const float* bp[3] = {(const float*)d_in[4],  (const float*)d_in[9],  (const float*)d_in[14]};
    const float* wsm[3] = {(const float*)d_in[5], (const float*)d_in[10], (const float*)d_in[15]};
    const float* wn[3] = {(const float*)d_in[6],  (const float*)d_in[11], (const float*)d_in[16]};
    const float* bb[3] = {(const float*)d_in[7],  (const float*)d_in[12], (const float*)d_in[17]};
    const float* gamma = (const float*)d_in[18];
    const float* beta  = (const float*)d_in[19];
    const float* wc    = (const float*)d_in[20];
    const float* bc    = (const float*)d_in[21];

    const size_t SZ = (size_t)N_NODES * F;          // 12.8M elements
    short* sbase = (short*)d_ws;
    short* B0  = sbase;
    short* B1  = sbase + SZ;
    short* B2  = sbase + 2 * SZ;
    short* Xbf = sbase + 3 * SZ;
    short* wp_p  = sbase + 4 * SZ;                  // 3 × 16384
    short* wsn_p = wp_p + 3 * 16384;                // 3 × 32768
    float* fbase = (float*)(wsn_p + 3 * 32768);     // 16B-aligned
    float* stats = fbase;                           // 256
    float* coef  = fbase + 256;                     // 256
    int* ibase = (int*)(fbase + 512);
    int* deg       = ibase;                         // 100000
    int* row_start = ibase + 100000;                // 100001
    int* cursor    = ibase + 200104;                // 100000
    int* esrc      = ibase + 300104;                // 1000000
    int* bsum      = ibase + 1300104;               // 128

    const int gGemm = (N_NODES + 127) / 128;        // 782
    const int gE    = (N_EDGES + 255) / 256;        // 3907
    const int gScan = (N_NODES + 1023) / 1024;      // 98
    const int gAgg  = ((N_NODES + 3) / 4) * 8;      // 200000 (node-groups x 8 slices)
    const long cvt4 = (long)(SZ / 4);               // 3.2M
    const long n2   = (long)(SZ / 2);               // 6.4M

    // ---- prep: bf16 node features + packed bf16 weights ----
    f32_to_bf16_kernel<<<(int)((cvt4 + 255) / 256), 256, 0, stream>>>(
        (const float4*)node_feat, (uint2*)Xbf, cvt4);
    for (int l = 0; l < 3; ++l)
        pack_weights3<<<192, 256, 0, stream>>>(wp[l], wsm[l], wn[l],
                                               wp_p + l * 16384, wsn_p + l * 32768);

    // ---- build CSR (graph static across layers) ----
    zero_kernel<<<98, 256, 0, stream>>>((float4*)deg, 25000);
    hist_kernel<<<gE, 256, 0, stream>>>(dst, deg);
    scan1_kernel<<<gScan, 256, 0, stream>>>(deg, bsum);
    scan2_kernel<<<1, 128, 0, stream>>>(bsum, gScan, row_start);
    scan3_kernel<<<gScan, 256, 0, stream>>>(deg, bsum, row_start, cursor);
    scatter_xcd_kernel<<<4096, 256, 0, stream>>>(src, dst, cursor, esrc);

    // ---- 3 SAGE layers ----
    const short* Xl[3]  = {Xbf, B0, B1};
    short* hpb[3]       = {B0, B1, B0};              // sliced layout
    short* aggb[3]      = {B1, B2, B2};              // sliced layout
    short* Yb[3]        = {B0, B1, B0};              // row-major
    for (int l = 0; l < 3; ++l) {
        const short* X = Xl[l];
        gemm_mfma<4, true, false><<<gGemm, 256, 0, stream>>>(X, (const short*)nullptr,
            wp_p + l * 16384, bp[l], (unsigned short*)hpb[l], N_NODES, 1);
        aggregate_max_sliced<<<gAgg, 256, 0, stream>>>(
            (const unsigned short*)hpb[l], row_start, esrc, (unsigned short*)aggb[l]);
        const int act = (l == 0) ? 2 : 0;
        gemm_mfma<8, false, true><<<gGemm, 256, 0, stream>>>(X, aggb[l],
            wsn_p + l * 32768, bb[l], (unsigned short*)Yb[l], N_NODES, act);
        if (l == 1) {
            zero_kernel<<<1, 256, 0, stream>>>((float4*)stats, 64);
            bn_stats_kernel<<<512, 256, 0, stream>>>(
                (const unsigned short*)Yb[l], stats, N_NODES);
            bn_finalize_kernel<<<1, 128, 0, stream>>>(stats, gamma, beta, coef);
            bn_apply_bf16<<<(int)((n2 + 255) / 256), 256, 0, stream>>>(
                (unsigned int*)Yb[l], coef, n2);
        }
    }
    classifier_kernel<<<(N_NODES + 15) / 16, 256, 0, stream>>>(
        (const unsigned short*)B0, wc, bc, (float*)d_out, N_NODES);
}

// Round 12
// 560.613 us; speedup vs baseline: 1.6696x; 1.6696x over previous
//
#include <hip/hip_runtime.h>

// GraphSAGE-pool ×3 + BN + classifier, bf16 activations + MFMA GEMMs.
// R12 = R10 (sliced aggregation reverted: 8x wave-task overhead made it
// instruction-bound, 176 us) + clamped single-round gather in aggregate:
// idx = min(base+j, end-1 -> beg) re-maxes edge beg (idempotent for max),
// so 16 independent gathers issue in one latency round, no tail ladder.

#define N_NODES 100000
#define N_EDGES 1000000
#define F 128
#define NEG_SLOPE 0.01f
#define BN_EPS 1e-5f
#define NODES_PER_XCD 12500

typedef __attribute__((ext_vector_type(8))) short bf16x8;
typedef __attribute__((ext_vector_type(4))) float f32x4;

typedef __attribute__((address_space(3))) unsigned int as3_uint;
typedef __attribute__((address_space(1))) const unsigned int as1_cuint;

__device__ __forceinline__ void gload16(const void* g, void* l) {
    __builtin_amdgcn_global_load_lds((as1_cuint*)g, (as3_uint*)l, 16, 0, 0);
}

__device__ __forceinline__ unsigned short f2bf(float f) {
    unsigned int u = __float_as_uint(f);
    u += 0x7fff + ((u >> 16) & 1);          // RNE
    return (unsigned short)(u >> 16);
}
__device__ __forceinline__ float bf2f(unsigned short h) {
    return __uint_as_float(((unsigned int)h) << 16);
}

// ---------------- zero fill ----------------
__global__ __launch_bounds__(256) void zero_kernel(float4* __restrict__ p, long n4) {
    long i = (long)blockIdx.x * 256 + threadIdx.x;
    if (i < n4) p[i] = make_float4(0.f, 0.f, 0.f, 0.f);
}

// ---------------- fp32 -> bf16 convert ----------------
__global__ __launch_bounds__(256) void f32_to_bf16_kernel(
    const float4* __restrict__ in, uint2* __restrict__ out, long n4)
{
    long i = (long)blockIdx.x * 256 + threadIdx.x;
    if (i >= n4) return;
    float4 v = in[i];
    uint2 o;
    o.x = (unsigned)f2bf(v.x) | ((unsigned)f2bf(v.y) << 16);
    o.y = (unsigned)f2bf(v.z) | ((unsigned)f2bf(v.w) << 16);
    out[i] = o;
}

// ---------------- weight pack: f32 [128][128] -> bf16 frag-order [16][128][8] ----------------
__global__ __launch_bounds__(256) void pack_weights3(
    const float* __restrict__ wp, const float* __restrict__ wss,
    const float* __restrict__ wn, short* __restrict__ wp_p, short* __restrict__ wsn_p)
{
    const int i = blockIdx.x * 256 + threadIdx.x;   // 0..49151
    if (i >= 3 * 16384) return;
    const int mat = i >> 14;
    const int idx = i & 16383;
    const int k = idx >> 7, n = idx & 127;
    const float* srcm = mat == 0 ? wp : (mat == 1 ? wss : wn);
    const int slot = ((k >> 3) * 128 + n) * 8 + (k & 7);
    if (mat == 0) wp_p[slot] = (short)f2bf(srcm[idx]);
    else wsn_p[(mat == 2 ? 16 * 128 * 8 : 0) + slot] = (short)f2bf(srcm[idx]);
}

// ---------------- MFMA GEMM, m97-style; epilogue aliased into tile LDS (R10-verified) ----------------
template<int NKS>
__global__ __launch_bounds__(256) void gemm_mfma(
    const short* __restrict__ A1, const short* __restrict__ A2,
    const short* __restrict__ Bp, const float* __restrict__ bias,
    unsigned short* __restrict__ Cout, int n_rows, int act)
{
    constexpr int S = NKS / 2;                   // BK=64 steps
    __shared__ short tile[2 * 8192];             // 2 x (128 rows x 64 cols); reused as epilogue bounce

    const int tid = threadIdx.x;
    const int wave = tid >> 6;
    const int lane = tid & 63;
    const int m = lane & 15, q = lane >> 4;
    const int r0 = blockIdx.x * 128;
    const int rw = (wave >> 1) * 64;             // wave row-quadrant offset
    const int r0q = r0 + rw;
    const int c0 = (wave & 1) * 64;
    const int gchunk = (tid & 7) ^ ((tid >> 3) & 7);

    f32x4 acc[4][4];
#pragma unroll
    for (int i = 0; i < 4; ++i)
#pragma unroll
        for (int j = 0; j < 4; ++j)
#pragma unroll
            for (int r = 0; r < 4; ++r) acc[i][j][r] = 0.f;

    auto stage = [&](int s, int buf) {
        const short* Ap = (NKS == 8 && s >= 2) ? A2 : A1;
        const int kbase = (s & 1) * 64;          // shorts
#pragma unroll
        for (int p = 0; p < 4; ++p) {
            int row = r0 + (tid >> 3) + 32 * p;
            row = min(row, n_rows - 1);
            gload16(Ap + (size_t)row * F + kbase + gchunk * 8,
                    &tile[buf * 8192 + p * 2048 + tid * 8]);
        }
    };

    stage(0, 0);
    __syncthreads();

    for (int s = 0; s < S; ++s) {
        if (s + 1 < S) stage(s + 1, (s + 1) & 1);
        const short* tb = &tile[(s & 1) * 8192];
#pragma unroll
        for (int ks2 = 0; ks2 < 2; ++ks2) {
            const int ks32 = s * 2 + ks2;
            bf16x8 b[4], a[4];
#pragma unroll
            for (int ni = 0; ni < 4; ++ni)
                b[ni] = *(const bf16x8*)(Bp + ((size_t)(ks32 * 4 + q) * F + c0 + ni * 16 + m) * 8);
#pragma unroll
            for (int mi = 0; mi < 4; ++mi)
                a[mi] = *(const bf16x8*)(tb + (rw + mi * 16 + m) * 64 + (((ks2 * 4 + q) ^ (m & 7)) << 3));
#pragma unroll
            for (int mi = 0; mi < 4; ++mi)
#pragma unroll
                for (int ni = 0; ni < 4; ++ni)
                    acc[mi][ni] = __builtin_amdgcn_mfma_f32_16x16x32_bf16(a[mi], b[ni], acc[mi][ni], 0, 0, 0);
        }
        __syncthreads();   // after last step: all reads of tile done -> safe to alias
    }

    float bv[4];
#pragma unroll
    for (int ni = 0; ni < 4; ++ni) bv[ni] = bias[c0 + ni * 16 + m];

    short* ep = &tile[wave * 1280];              // aliased onto dead A-tile buffer
    const int colc_lo = m >> 3, cin = m & 7;
#pragma unroll
    for (int mi = 0; mi < 4; ++mi) {
#pragma unroll
        for (int ni = 0; ni < 4; ++ni) {
            const int colc = 2 * ni + colc_lo;
#pragma unroll
            for (int rg = 0; rg < 4; ++rg) {
                const int row16 = q * 4 + rg;
                float v = acc[mi][ni][rg] + bv[ni];
                if (act == 1) v = v > 0.f ? v : 0.f;
                else if (act == 2) v = v > 0.f ? v : v * NEG_SLOPE;
                ep[row16 * 80 + ((colc ^ (row16 & 7)) << 3) + cin] = (short)f2bf(v);
            }
        }
        __syncthreads();
#pragma unroll
        for (int p = 0; p < 2; ++p) {
            const int lrow = (lane >> 3) + 8 * p;
            bf16x8 vv = *(const bf16x8*)&ep[lrow * 80 + (((lane & 7) ^ (lrow & 7)) << 3)];
            const int grow = r0q + mi * 16 + lrow;
            if (grow < n_rows)
                *(bf16x8*)(Cout + (size_t)grow * F + c0 + ((lane & 7) << 3)) = vv;
        }
        __syncthreads();
    }
}

// ---------------- CSR build (R10-verified) ----------------
__global__ __launch_bounds__(256) void hist_kernel(const int* __restrict__ dst, int* __restrict__ deg) {
    const int e = blockIdx.x * 256 + threadIdx.x;
    if (e < N_EDGES) atomicAdd(&deg[__builtin_nontemporal_load(&dst[e])], 1);
}

__global__ __launch_bounds__(256) void scan1_kernel(const int* __restrict__ deg, int* __restrict__ bsum) {
    __shared__ int sh[256];
    const int t = threadIdx.x;
    const int base = blockIdx.x * 1024 + t * 4;
    int s = 0;
#pragma unroll
    for (int j = 0; j < 4; ++j) s += (base + j < N_NODES) ? deg[base + j] : 0;
    sh[t] = s; __syncthreads();
    for (int off = 128; off; off >>= 1) {
        if (t < off) sh[t] += sh[t + off];
        __syncthreads();
    }
    if (t == 0) bsum[blockIdx.x] = sh[0];
}

__global__ __launch_bounds__(128) void scan2_kernel(int* __restrict__ bsum, int nb, int* __restrict__ row_start) {
    __shared__ int sh[128];
    const int t = threadIdx.x;
    sh[t] = (t < nb) ? bsum[t] : 0;
    __syncthreads();
    for (int off = 1; off < 128; off <<= 1) {
        int x = (t >= off) ? sh[t - off] : 0;
        __syncthreads();
        if (t >= off) sh[t] += x;
        __syncthreads();
    }
    if (t < nb) bsum[t] = t ? sh[t - 1] : 0;
    if (t == 0) row_start[N_NODES] = N_EDGES;
}

__global__ __launch_bounds__(256) void scan3_kernel(
    const int* __restrict__ deg, const int* __restrict__ boff,
    int* __restrict__ row_start, int* __restrict__ cursor)
{
    __shared__ int sh[256];
    const int t = threadIdx.x;
    const int base = blockIdx.x * 1024 + t * 4;
    int v[4]; int s = 0;
#pragma unroll
    for (int j = 0; j < 4; ++j) { v[j] = (base + j < N_NODES) ? deg[base + j] : 0; s += v[j]; }
    sh[t] = s; __syncthreads();
    for (int off = 1; off < 256; off <<= 1) {
        int x = (t >= off) ? sh[t - off] : 0;
        __syncthreads();
        if (t >= off) sh[t] += x;
        __syncthreads();
    }
    int excl = (t ? sh[t - 1] : 0) + boff[blockIdx.x];
#pragma unroll
    for (int j = 0; j < 4; ++j) {
        if (base + j < N_NODES) { row_start[base + j] = excl; cursor[base + j] = excl; }
        excl += v[j];
    }
}

#define CHUNK_E2 1954
__global__ __launch_bounds__(256) void scatter_xcd_kernel(
    const int* __restrict__ src, const int* __restrict__ dst,
    int* __restrict__ cursor, int* __restrict__ esrc)
{
    const int range = blockIdx.x & 7;
    const int chunk = blockIdx.x >> 3;            // 0..511
    const int lo = range * NODES_PER_XCD;
    const int e0 = chunk * CHUNK_E2;
    const int e1 = min(e0 + CHUNK_E2, N_EDGES);
    for (int e = e0 + threadIdx.x; e < e1; e += 256) {
        const int d = dst[e];
        if ((unsigned)(d - lo) < NODES_PER_XCD) {
            const int pos = atomicAdd(&cursor[d], 1);
            esrc[pos] = src[e];
        }
    }
}

// ---------------- aggregation: wave per node, clamped single-round gather ----------------
// idx clamps to beg for j >= deg: re-maxing edge beg is idempotent, so all 16
// gathers are independent (one latency round for deg<=16, ~97% of nodes).
__global__ __launch_bounds__(256) void aggregate_max_bf16(
    const unsigned int* __restrict__ hp, const int* __restrict__ row_start,
    const int* __restrict__ esrc, unsigned int* __restrict__ agg)
{
    const int node = blockIdx.x * 4 + (threadIdx.x >> 6);
    if (node >= N_NODES) return;
    const int lane = threadIdx.x & 63;
    const int beg = row_start[node], end = row_start[node + 1];
    unsigned int m0 = 0, m1 = 0;
    for (int base = beg; base < end; base += 16) {
        int s[16];
#pragma unroll
        for (int j = 0; j < 16; ++j) {
            const int t = base + j;
            s[j] = esrc[(t < end) ? t : beg];
        }
        unsigned int v[16];
#pragma unroll
        for (int j = 0; j < 16; ++j) v[j] = hp[(size_t)s[j] * 64 + lane];
#pragma unroll
        for (int j = 0; j < 16; ++j) {
            m0 = max(m0, v[j] & 0xffffu);
            m1 = max(m1, v[j] >> 16);
        }
    }
    agg[(size_t)node * 64 + lane] = m0 | (m1 << 16);
}

// ---------------- BN stats (verified R8) ----------------
#define BN_ROWS_PER_BLOCK 196
__global__ __launch_bounds__(256) void bn_stats_kernel(
    const unsigned short* __restrict__ x, float* __restrict__ stats, int n)
{
    const int tid = threadIdx.x;
    const int wave = tid >> 6, lane = tid & 63;
    const int rgrp = lane >> 4;
    const int c16 = lane & 15;
    const int rbase = blockIdx.x * BN_ROWS_PER_BLOCK;
    const int rend = min(rbase + BN_ROWS_PER_BLOCK, n);

    float s[8], ss[8];
#pragma unroll
    for (int j = 0; j < 8; ++j) { s[j] = 0.f; ss[j] = 0.f; }

    for (int r = rbase + wave * 4 + rgrp; r < rend; r += 16) {
        const uint4 v = *(const uint4*)(x + (size_t)r * F + c16 * 8);
        const unsigned int w[4] = {v.x, v.y, v.z, v.w};
#pragma unroll
        for (int u = 0; u < 4; ++u) {
            const float f0 = bf2f((unsigned short)(w[u] & 0xffffu));
            const float f1 = bf2f((unsigned short)(w[u] >> 16));
            s[2*u]   += f0; ss[2*u]   = fmaf(f0, f0, ss[2*u]);
            s[2*u+1] += f1; ss[2*u+1] = fmaf(f1, f1, ss[2*u+1]);
        }
    }
#pragma unroll
    for (int j = 0; j < 8; ++j) {
        s[j]  += __shfl_down(s[j], 32);  s[j]  += __shfl_down(s[j], 16);
        ss[j] += __shfl_down(ss[j], 32); ss[j] += __shfl_down(ss[j], 16);
    }
    __shared__ float sh[4][16][16];
    if (lane < 16) {
#pragma unroll
        for (int j = 0; j < 8; ++j) {
            sh[wave][c16][2*j]     = s[j];
            sh[wave][c16][2*j + 1] = ss[j];
        }
    }
    __syncthreads();
    const float tot = sh[0][tid >> 4][tid & 15] + sh[1][tid >> 4][tid & 15]
                    + sh[2][tid >> 4][tid & 15] + sh[3][tid >> 4][tid & 15];
    const int col = (tid >> 4) * 8 + ((tid >> 1) & 7);
    atomicAdd(&stats[(tid & 1) * 128 + col], tot);
}

__global__ void bn_finalize_kernel(
    const float* __restrict__ stats, const float* __restrict__ gamma,
    const float* __restrict__ beta, float* __restrict__ coef)
{
    const int c = threadIdx.x;
    const float mean = stats[c] * (1.f / N_NODES);
    const float var = stats[128 + c] * (1.f / N_NODES) - mean * mean;
    const float scale = gamma[c] * rsqrtf(var + BN_EPS);
    coef[c] = scale;
    coef[128 + c] = fmaf(-mean, scale, beta[c]);
}

__global__ __launch_bounds__(256) void bn_apply_bf16(
    unsigned int* __restrict__ x, const float* __restrict__ coef, long n2)
{
    __shared__ float sc[128], sf[128];
    if (threadIdx.x < 128) {
        sc[threadIdx.x] = coef[threadIdx.x];
        sf[threadIdx.x] = coef[128 + threadIdx.x];
    }
    __syncthreads();
    const long i = (long)blockIdx.x * 256 + threadIdx.x;
    if (i >= n2) return;
    const unsigned int v = x[i];
    const int c0 = (int)(i & 63) * 2;
    float a = fmaf(bf2f((unsigned short)(v & 0xffffu)), sc[c0], sf[c0]);
    float b = fmaf(bf2f((unsigned short)(v >> 16)), sc[c0 + 1], sf[c0 + 1]);
    a = a > 0.f ? a : a * NEG_SLOPE;
    b = b > 0.f ? b : b * NEG_SLOPE;
    x[i] = (unsigned)f2bf(a) | ((unsigned)f2bf(b) << 16);
}

// ---------------- classifier ----------------
__global__ __launch_bounds__(256) void classifier_kernel(
    const unsigned short* __restrict__ X, const float* __restrict__ Wc,
    const float* __restrict__ bc, float* __restrict__ out, int n)
{
    __shared__ float Wl[2048];
    __shared__ float Xs[16 * 132];
    const int tid = threadIdx.x;
    for (int i = tid; i < 2048; i += 256) Wl[i] = Wc[i];
    const int r0 = blockIdx.x * 16;
    for (int i = tid; i < 2048; i += 256) {
        const int row = i >> 7, col = i & 127;
        const int gr = r0 + row;
        Xs[row * 132 + col] = (gr < n) ? bf2f(X[(size_t)gr * F + col]) : 0.f;
    }
    __syncthreads();
    const int rl = tid >> 4, c = tid & 15;
    const int r = r0 + rl;
    if (r >= n) return;
    float s = bc[c];
    const float* xr = &Xs[rl * 132];
#pragma unroll
    for (int k = 0; k < 128; ++k) s = fmaf(xr[k], Wl[k * 16 + c], s);
    out[(size_t)r * 16 + c] = s;
}

extern "C" void kernel_launch(void* const* d_in, const int* in_sizes, int n_in,
                              void* d_out, int out_size, void* d_ws, size_t ws_size,
                              hipStream_t stream) {
    const float* node_feat = (const float*)d_in[0];
    const int* src = (const int*)d_in[1];
    const int* dst = (const int*)d_in[2];
    const float* wp[3] = {(const float*)d_in[3],  (const float*)d_in[8],  (const float*)d_in[13]};
    const float* bp[3] = {(const float*)d_in[4],  (const float*)d_in[9],  (const float*)d_in[14]};
    const float* wsm[3] = {(const float*)d_in[5], (const float*)d_in[10], (const float*)d_in[15]};
    const float* wn[3] = {(const float*)d_in[6],  (const float*)d_in[11], (const float*)d_in[16]};
    const float* bb[3] = {(const float*)d_in[7],  (const float*)d_in[12], (const float*)d_in[17]};
    const float* gamma = (const float*)d_in[18];
    const float* beta  = (const float*)d_in[19];
    const float* wc    = (const float*)d_in[20];
    const float* bc    = (const float*)d_in[21];

    const size_t SZ = (size_t)N_NODES * F;          // 12.8M elements
    short* sbase = (short*)d_ws;
    short* B0  = sbase;
    short* B1  = sbase + SZ;
    short* B2  = sbase + 2 * SZ;
    short* Xbf = sbase + 3 * SZ;
    short* wp_p  = sbase + 4 * SZ;                  // 3 × 16384
    short* wsn_p = wp_p + 3 * 16384;                // 3 × 32768
    float* fbase = (float*)(wsn_p + 3 * 32768);     // 16B-aligned
    float* stats = fbase;                           // 256
    float* coef  = fbase + 256;                     // 256
    int* ibase = (int*)(fbase + 512);
    int* deg       = ibase;                         // 100000
    int* row_start = ibase + 100000;                // 100001
    int* cursor    = ibase + 200104;                // 100000
    int* esrc      = ibase + 300104;                // 1000000
    int* bsum      = ibase + 1300104;               // 128

    const int gGemm = (N_NODES + 127) / 128;        // 782
    const int gE    = (N_EDGES + 255) / 256;        // 3907
    const int gScan = (N_NODES + 1023) / 1024;      // 98
    const int gAgg  = (N_NODES + 3) / 4;            // 25000
    const long cvt4 = (long)(SZ / 4);               // 3.2M
    const long n2   = (long)(SZ / 2);               // 6.4M

    // ---- prep: bf16 node features + packed bf16 weights ----
    f32_to_bf16_kernel<<<(int)((cvt4 + 255) / 256), 256, 0, stream>>>(
        (const float4*)node_feat, (uint2*)Xbf, cvt4);
    for (int l = 0; l < 3; ++l)
        pack_weights3<<<192, 256, 0, stream>>>(wp[l], wsm[l], wn[l],
                                               wp_p + l * 16384, wsn_p + l * 32768);

    // ---- build CSR (graph static across layers) ----
    zero_kernel<<<98, 256, 0, stream>>>((float4*)deg, 25000);
    hist_kernel<<<gE, 256, 0, stream>>>(dst, deg);
    scan1_kernel<<<gScan, 256, 0, stream>>>(deg, bsum);
    scan2_kernel<<<1, 128, 0, stream>>>(bsum, gScan, row_start);
    scan3_kernel<<<gScan, 256, 0, stream>>>(deg, bsum, row_start, cursor);
    scatter_xcd_kernel<<<4096, 256, 0, stream>>>(src, dst, cursor, esrc);

    // ---- 3 SAGE layers ----
    const short* Xl[3]  = {Xbf, B0, B1};
    short* hpb[3]       = {B0, B1, B0};
    short* aggb[3]      = {B1, B2, B2};
    short* Yb[3]        = {B0, B1, B0};
    for (int l = 0; l < 3; ++l) {
        const short* X = Xl[l];
        gemm_mfma<4><<<gGemm, 256, 0, stream>>>(X, (const short*)nullptr,
            wp_p + l * 16384, bp[l], (unsigned short*)hpb[l], N_NODES, 1);
        aggregate_max_bf16<<<gAgg, 256, 0, stream>>>(
            (const unsigned int*)hpb[l], row_start, esrc, (unsigned int*)aggb[l]);
        const int act = (l == 0) ? 2 : 0;
        gemm_mfma<8><<<gGemm, 256, 0, stream>>>(X, aggb[l],
            wsn_p + l * 32768, bb[l], (unsigned short*)Yb[l], N_NODES, act);
        if (l == 1) {
            zero_kernel<<<1, 256, 0, stream>>>((float4*)stats, 64);
            bn_stats_kernel<<<512, 256, 0, stream>>>(
                (const unsigned short*)Yb[l], stats, N_NODES);
            bn_finalize_kernel<<<1, 128, 0, stream>>>(stats, gamma, beta, coef);
            bn_apply_bf16<<<(int)((n2 + 255) / 256), 256, 0, stream>>>(
                (unsigned int*)Yb[l], coef, n2);
        }
    }
    classifier_kernel<<<(N_NODES + 15) / 16, 256, 0, stream>>>(
        (const unsigned short*)B0, wc, bc, (float*)d_out, N_NODES);
}

// Round 13
// 552.837 us; speedup vs baseline: 1.6931x; 1.0141x over previous
//
#include <hip/hip_runtime.h>

// GraphSAGE-pool ×3 + BN + classifier, bf16 activations + MFMA GEMMs.
// R13 = R12 + packed max in aggregate: v_pk_max_u16 (via
// __builtin_elementwise_max on ushort2) replaces the scalar and/shift/max
// unpack chain (R12: VALUBusy 62% co-limited the gather kernel). bf16>=0
// => per-half unsigned bit-max == numeric max (same invariant as R3+).

#define N_NODES 100000
#define N_EDGES 1000000
#define F 128
#define NEG_SLOPE 0.01f
#define BN_EPS 1e-5f
#define NODES_PER_XCD 12500

typedef __attribute__((ext_vector_type(8))) short bf16x8;
typedef __attribute__((ext_vector_type(4))) float f32x4;
typedef __attribute__((ext_vector_type(2))) unsigned short u16x2;

typedef __attribute__((address_space(3))) unsigned int as3_uint;
typedef __attribute__((address_space(1))) const unsigned int as1_cuint;

__device__ __forceinline__ void gload16(const void* g, void* l) {
    __builtin_amdgcn_global_load_lds((as1_cuint*)g, (as3_uint*)l, 16, 0, 0);
}

__device__ __forceinline__ unsigned short f2bf(float f) {
    unsigned int u = __float_as_uint(f);
    u += 0x7fff + ((u >> 16) & 1);          // RNE
    return (unsigned short)(u >> 16);
}
__device__ __forceinline__ float bf2f(unsigned short h) {
    return __uint_as_float(((unsigned int)h) << 16);
}

// ---------------- zero fill ----------------
__global__ __launch_bounds__(256) void zero_kernel(float4* __restrict__ p, long n4) {
    long i = (long)blockIdx.x * 256 + threadIdx.x;
    if (i < n4) p[i] = make_float4(0.f, 0.f, 0.f, 0.f);
}

// ---------------- fp32 -> bf16 convert ----------------
__global__ __launch_bounds__(256) void f32_to_bf16_kernel(
    const float4* __restrict__ in, uint2* __restrict__ out, long n4)
{
    long i = (long)blockIdx.x * 256 + threadIdx.x;
    if (i >= n4) return;
    float4 v = in[i];
    uint2 o;
    o.x = (unsigned)f2bf(v.x) | ((unsigned)f2bf(v.y) << 16);
    o.y = (unsigned)f2bf(v.z) | ((unsigned)f2bf(v.w) << 16);
    out[i] = o;
}

// ---------------- weight pack: f32 [128][128] -> bf16 frag-order [16][128][8] ----------------
__global__ __launch_bounds__(256) void pack_weights3(
    const float* __restrict__ wp, const float* __restrict__ wss,
    const float* __restrict__ wn, short* __restrict__ wp_p, short* __restrict__ wsn_p)
{
    const int i = blockIdx.x * 256 + threadIdx.x;   // 0..49151
    if (i >= 3 * 16384) return;
    const int mat = i >> 14;
    const int idx = i & 16383;
    const int k = idx >> 7, n = idx & 127;
    const float* srcm = mat == 0 ? wp : (mat == 1 ? wss : wn);
    const int slot = ((k >> 3) * 128 + n) * 8 + (k & 7);
    if (mat == 0) wp_p[slot] = (short)f2bf(srcm[idx]);
    else wsn_p[(mat == 2 ? 16 * 128 * 8 : 0) + slot] = (short)f2bf(srcm[idx]);
}

// ---------------- MFMA GEMM, m97-style; epilogue aliased into tile LDS (R10-verified) ----------------
template<int NKS>
__global__ __launch_bounds__(256) void gemm_mfma(
    const short* __restrict__ A1, const short* __restrict__ A2,
    const short* __restrict__ Bp, const float* __restrict__ bias,
    unsigned short* __restrict__ Cout, int n_rows, int act)
{
    constexpr int S = NKS / 2;                   // BK=64 steps
    __shared__ short tile[2 * 8192];             // 2 x (128 rows x 64 cols); reused as epilogue bounce

    const int tid = threadIdx.x;
    const int wave = tid >> 6;
    const int lane = tid & 63;
    const int m = lane & 15, q = lane >> 4;
    const int r0 = blockIdx.x * 128;
    const int rw = (wave >> 1) * 64;             // wave row-quadrant offset
    const int r0q = r0 + rw;
    const int c0 = (wave & 1) * 64;
    const int gchunk = (tid & 7) ^ ((tid >> 3) & 7);

    f32x4 acc[4][4];
#pragma unroll
    for (int i = 0; i < 4; ++i)
#pragma unroll
        for (int j = 0; j < 4; ++j)
#pragma unroll
            for (int r = 0; r < 4; ++r) acc[i][j][r] = 0.f;

    auto stage = [&](int s, int buf) {
        const short* Ap = (NKS == 8 && s >= 2) ? A2 : A1;
        const int kbase = (s & 1) * 64;          // shorts
#pragma unroll
        for (int p = 0; p < 4; ++p) {
            int row = r0 + (tid >> 3) + 32 * p;
            row = min(row, n_rows - 1);
            gload16(Ap + (size_t)row * F + kbase + gchunk * 8,
                    &tile[buf * 8192 + p * 2048 + tid * 8]);
        }
    };

    stage(0, 0);
    __syncthreads();

    for (int s = 0; s < S; ++s) {
        if (s + 1 < S) stage(s + 1, (s + 1) & 1);
        const short* tb = &tile[(s & 1) * 8192];
#pragma unroll
        for (int ks2 = 0; ks2 < 2; ++ks2) {
            const int ks32 = s * 2 + ks2;
            bf16x8 b[4], a[4];
#pragma unroll
            for (int ni = 0; ni < 4; ++ni)
                b[ni] = *(const bf16x8*)(Bp + ((size_t)(ks32 * 4 + q) * F + c0 + ni * 16 + m) * 8);
#pragma unroll
            for (int mi = 0; mi < 4; ++mi)
                a[mi] = *(const bf16x8*)(tb + (rw + mi * 16 + m) * 64 + (((ks2 * 4 + q) ^ (m & 7)) << 3));
#pragma unroll
            for (int mi = 0; mi < 4; ++mi)
#pragma unroll
                for (int ni = 0; ni < 4; ++ni)
                    acc[mi][ni] = __builtin_amdgcn_mfma_f32_16x16x32_bf16(a[mi], b[ni], acc[mi][ni], 0, 0, 0);
        }
        __syncthreads();   // after last step: all reads of tile done -> safe to alias
    }

    float bv[4];
#pragma unroll
    for (int ni = 0; ni < 4; ++ni) bv[ni] = bias[c0 + ni * 16 + m];

    short* ep = &tile[wave * 1280];              // aliased onto dead A-tile buffer
    const int colc_lo = m >> 3, cin = m & 7;
#pragma unroll
    for (int mi = 0; mi < 4; ++mi) {
#pragma unroll
        for (int ni = 0; ni < 4; ++ni) {
            const int colc = 2 * ni + colc_lo;
#pragma unroll
            for (int rg = 0; rg < 4; ++rg) {
                const int row16 = q * 4 + rg;
                float v = acc[mi][ni][rg] + bv[ni];
                if (act == 1) v = v > 0.f ? v : 0.f;
                else if (act == 2) v = v > 0.f ? v : v * NEG_SLOPE;
                ep[row16 * 80 + ((colc ^ (row16 & 7)) << 3) + cin] = (short)f2bf(v);
            }
        }
        __syncthreads();
#pragma unroll
        for (int p = 0; p < 2; ++p) {
            const int lrow = (lane >> 3) + 8 * p;
            bf16x8 vv = *(const bf16x8*)&ep[lrow * 80 + (((lane & 7) ^ (lrow & 7)) << 3)];
            const int grow = r0q + mi * 16 + lrow;
            if (grow < n_rows)
                *(bf16x8*)(Cout + (size_t)grow * F + c0 + ((lane & 7) << 3)) = vv;
        }
        __syncthreads();
    }
}

// ---------------- CSR build (R10-verified) ----------------
__global__ __launch_bounds__(256) void hist_kernel(const int* __restrict__ dst, int* __restrict__ deg) {
    const int e = blockIdx.x * 256 + threadIdx.x;
    if (e < N_EDGES) atomicAdd(&deg[__builtin_nontemporal_load(&dst[e])], 1);
}

__global__ __launch_bounds__(256) void scan1_kernel(const int* __restrict__ deg, int* __restrict__ bsum) {
    __shared__ int sh[256];
    const int t = threadIdx.x;
    const int base = blockIdx.x * 1024 + t * 4;
    int s = 0;
#pragma unroll
    for (int j = 0; j < 4; ++j) s += (base + j < N_NODES) ? deg[base + j] : 0;
    sh[t] = s; __syncthreads();
    for (int off = 128; off; off >>= 1) {
        if (t < off) sh[t] += sh[t + off];
        __syncthreads();
    }
    if (t == 0) bsum[blockIdx.x] = sh[0];
}

__global__ __launch_bounds__(128) void scan2_kernel(int* __restrict__ bsum, int nb, int* __restrict__ row_start) {
    __shared__ int sh[128];
    const int t = threadIdx.x;
    sh[t] = (t < nb) ? bsum[t] : 0;
    __syncthreads();
    for (int off = 1; off < 128; off <<= 1) {
        int x = (t >= off) ? sh[t - off] : 0;
        __syncthreads();
        if (t >= off) sh[t] += x;
        __syncthreads();
    }
    if (t < nb) bsum[t] = t ? sh[t - 1] : 0;
    if (t == 0) row_start[N_NODES] = N_EDGES;
}

__global__ __launch_bounds__(256) void scan3_kernel(
    const int* __restrict__ deg, const int* __restrict__ boff,
    int* __restrict__ row_start, int* __restrict__ cursor)
{
    __shared__ int sh[256];
    const int t = threadIdx.x;
    const int base = blockIdx.x * 1024 + t * 4;
    int v[4]; int s = 0;
#pragma unroll
    for (int j = 0; j < 4; ++j) { v[j] = (base + j < N_NODES) ? deg[base + j] : 0; s += v[j]; }
    sh[t] = s; __syncthreads();
    for (int off = 1; off < 256; off <<= 1) {
        int x = (t >= off) ? sh[t - off] : 0;
        __syncthreads();
        if (t >= off) sh[t] += x;
        __syncthreads();
    }
    int excl = (t ? sh[t - 1] : 0) + boff[blockIdx.x];
#pragma unroll
    for (int j = 0; j < 4; ++j) {
        if (base + j < N_NODES) { row_start[base + j] = excl; cursor[base + j] = excl; }
        excl += v[j];
    }
}

#define CHUNK_E2 1954
__global__ __launch_bounds__(256) void scatter_xcd_kernel(
    const int* __restrict__ src, const int* __restrict__ dst,
    int* __restrict__ cursor, int* __restrict__ esrc)
{
    const int range = blockIdx.x & 7;
    const int chunk = blockIdx.x >> 3;            // 0..511
    const int lo = range * NODES_PER_XCD;
    const int e0 = chunk * CHUNK_E2;
    const int e1 = min(e0 + CHUNK_E2, N_EDGES);
    for (int e = e0 + threadIdx.x; e < e1; e += 256) {
        const int d = dst[e];
        if ((unsigned)(d - lo) < NODES_PER_XCD) {
            const int pos = atomicAdd(&cursor[d], 1);
            esrc[pos] = src[e];
        }
    }
}

// ---------------- aggregation: wave per node, clamped single-round gather, pk_max ----------------
__global__ __launch_bounds__(256) void aggregate_max_bf16(
    const unsigned int* __restrict__ hp, const int* __restrict__ row_start,
    const int* __restrict__ esrc, unsigned int* __restrict__ agg)
{
    const int node = blockIdx.x * 4 + (threadIdx.x >> 6);
    if (node >= N_NODES) return;
    const int lane = threadIdx.x & 63;
    const int beg = row_start[node], end = row_start[node + 1];
    u16x2 mm = (u16x2)0;
    for (int base = beg; base < end; base += 16) {
        int s[16];
#pragma unroll
        for (int j = 0; j < 16; ++j) {
            const int t = base + j;
            s[j] = esrc[(t < end) ? t : beg];
        }
        unsigned int v[16];
#pragma unroll
        for (int j = 0; j < 16; ++j) v[j] = hp[(size_t)s[j] * 64 + lane];
#pragma unroll
        for (int j = 0; j < 16; ++j)
            mm = __builtin_elementwise_max(mm, __builtin_bit_cast(u16x2, v[j]));   // v_pk_max_u16
    }
    agg[(size_t)node * 64 + lane] = __builtin_bit_cast(unsigned int, mm);
}

// ---------------- BN stats (verified R8) ----------------
#define BN_ROWS_PER_BLOCK 196
__global__ __launch_bounds__(256) void bn_stats_kernel(
    const unsigned short* __restrict__ x, float* __restrict__ stats, int n)
{
    const int tid = threadIdx.x;
    const int wave = tid >> 6, lane = tid & 63;
    const int rgrp = lane >> 4;
    const int c16 = lane & 15;
    const int rbase = blockIdx.x * BN_ROWS_PER_BLOCK;
    const int rend = min(rbase + BN_ROWS_PER_BLOCK, n);

    float s[8], ss[8];
#pragma unroll
    for (int j = 0; j < 8; ++j) { s[j] = 0.f; ss[j] = 0.f; }

    for (int r = rbase + wave * 4 + rgrp; r < rend; r += 16) {
        const uint4 v = *(const uint4*)(x + (size_t)r * F + c16 * 8);
        const unsigned int w[4] = {v.x, v.y, v.z, v.w};
#pragma unroll
        for (int u = 0; u < 4; ++u) {
            const float f0 = bf2f((unsigned short)(w[u] & 0xffffu));
            const float f1 = bf2f((unsigned short)(w[u] >> 16));
            s[2*u]   += f0; ss[2*u]   = fmaf(f0, f0, ss[2*u]);
            s[2*u+1] += f1; ss[2*u+1] = fmaf(f1, f1, ss[2*u+1]);
        }
    }
#pragma unroll
    for (int j = 0; j < 8; ++j) {
        s[j]  += __shfl_down(s[j], 32);  s[j]  += __shfl_down(s[j], 16);
        ss[j] += __shfl_down(ss[j], 32); ss[j] += __shfl_down(ss[j], 16);
    }
    __shared__ float sh[4][16][16];
    if (lane < 16) {
#pragma unroll
        for (int j = 0; j < 8; ++j) {
            sh[wave][c16][2*j]     = s[j];
            sh[wave][c16][2*j + 1] = ss[j];
        }
    }
    __syncthreads();
    const float tot = sh[0][tid >> 4][tid & 15] + sh[1][tid >> 4][tid & 15]
                    + sh[2][tid >> 4][tid & 15] + sh[3][tid >> 4][tid & 15];
    const int col = (tid >> 4) * 8 + ((tid >> 1) & 7);
    atomicAdd(&stats[(tid & 1) * 128 + col], tot);
}

__global__ void bn_finalize_kernel(
    const float* __restrict__ stats, const float* __restrict__ gamma,
    const float* __restrict__ beta, float* __restrict__ coef)
{
    const int c = threadIdx.x;
    const float mean = stats[c] * (1.f / N_NODES);
    const float var = stats[128 + c] * (1.f / N_NODES) - mean * mean;
    const float scale = gamma[c] * rsqrtf(var + BN_EPS);
    coef[c] = scale;
    coef[128 + c] = fmaf(-mean, scale, beta[c]);
}

__global__ __launch_bounds__(256) void bn_apply_bf16(
    unsigned int* __restrict__ x, const float* __restrict__ coef, long n2)
{
    __shared__ float sc[128], sf[128];
    if (threadIdx.x < 128) {
        sc[threadIdx.x] = coef[threadIdx.x];
        sf[threadIdx.x] = coef[128 + threadIdx.x];
    }
    __syncthreads();
    const long i = (long)blockIdx.x * 256 + threadIdx.x;
    if (i >= n2) return;
    const unsigned int v = x[i];
    const int c0 = (int)(i & 63) * 2;
    float a = fmaf(bf2f((unsigned short)(v & 0xffffu)), sc[c0], sf[c0]);
    float b = fmaf(bf2f((unsigned short)(v >> 16)), sc[c0 + 1], sf[c0 + 1]);
    a = a > 0.f ? a : a * NEG_SLOPE;
    b = b > 0.f ? b : b * NEG_SLOPE;
    x[i] = (unsigned)f2bf(a) | ((unsigned)f2bf(b) << 16);
}

// ---------------- classifier ----------------
__global__ __launch_bounds__(256) void classifier_kernel(
    const unsigned short* __restrict__ X, const float* __restrict__ Wc,
    const float* __restrict__ bc, float* __restrict__ out, int n)
{
    __shared__ float Wl[2048];
    __shared__ float Xs[16 * 132];
    const int tid = threadIdx.x;
    for (int i = tid; i < 2048; i += 256) Wl[i] = Wc[i];
    const int r0 = blockIdx.x * 16;
    for (int i = tid; i < 2048; i += 256) {
        const int row = i >> 7, col = i & 127;
        const int gr = r0 + row;
        Xs[row * 132 + col] = (gr < n) ? bf2f(X[(size_t)gr * F + col]) : 0.f;
    }
    __syncthreads();
    const int rl = tid >> 4, c = tid & 15;
    const int r = r0 + rl;
    if (r >= n) return;
    float s = bc[c];
    const float* xr = &Xs[rl * 132];
#pragma unroll
    for (int k = 0; k < 128; ++k) s = fmaf(xr[k], Wl[k * 16 + c], s);
    out[(size_t)r * 16 + c] = s;
}

extern "C" void kernel_launch(void* const* d_in, const int* in_sizes, int n_in,
                              void* d_out, int out_size, void* d_ws, size_t ws_size,
                              hipStream_t stream) {
    const float* node_feat = (const float*)d_in[0];
    const int* src = (const int*)d_in[1];
    const int* dst = (const int*)d_in[2];
    const float* wp[3] = {(const float*)d_in[3],  (const float*)d_in[8],  (const float*)d_in[13]};
    const float* bp[3] = {(const float*)d_in[4],  (const float*)d_in[9],  (const float*)d_in[14]};
    const float* wsm[3] = {(const float*)d_in[5], (const float*)d_in[10], (const float*)d_in[15]};
    const float* wn[3] = {(const float*)d_in[6],  (const float*)d_in[11], (const float*)d_in[16]};
    const float* bb[3] = {(const float*)d_in[7],  (const float*)d_in[12], (const float*)d_in[17]};
    const float* gamma = (const float*)d_in[18];
    const float* beta  = (const float*)d_in[19];
    const float* wc    = (const float*)d_in[20];
    const float* bc    = (const float*)d_in[21];

    const size_t SZ = (size_t)N_NODES * F;          // 12.8M elements
    short* sbase = (short*)d_ws;
    short* B0  = sbase;
    short* B1  = sbase + SZ;
    short* B2  = sbase + 2 * SZ;
    short* Xbf = sbase + 3 * SZ;
    short* wp_p  = sbase + 4 * SZ;                  // 3 × 16384
    short* wsn_p = wp_p + 3 * 16384;                // 3 × 32768
    float* fbase = (float*)(wsn_p + 3 * 32768);     // 16B-aligned
    float* stats = fbase;                           // 256
    float* coef  = fbase + 256;                     // 256
    int* ibase = (int*)(fbase + 512);
    int* deg       = ibase;                         // 100000
    int* row_start = ibase + 100000;                // 100001
    int* cursor    = ibase + 200104;                // 100000
    int* esrc      = ibase + 300104;                // 1000000
    int* bsum      = ibase + 1300104;               // 128

    const int gGemm = (N_NODES + 127) / 128;        // 782
    const int gE    = (N_EDGES + 255) / 256;        // 3907
    const int gScan = (N_NODES + 1023) / 1024;      // 98
    const int gAgg  = (N_NODES + 3) / 4;            // 25000
    const long cvt4 = (long)(SZ / 4);               // 3.2M
    const long n2   = (long)(SZ / 2);               // 6.4M

    // ---- prep: bf16 node features + packed bf16 weights ----
    f32_to_bf16_kernel<<<(int)((cvt4 + 255) / 256), 256, 0, stream>>>(
        (const float4*)node_feat, (uint2*)Xbf, cvt4);
    for (int l = 0; l < 3; ++l)
        pack_weights3<<<192, 256, 0, stream>>>(wp[l], wsm[l], wn[l],
                                               wp_p + l * 16384, wsn_p + l * 32768);

    // ---- build CSR (graph static across layers) ----
    zero_kernel<<<98, 256, 0, stream>>>((float4*)deg, 25000);
    hist_kernel<<<gE, 256, 0, stream>>>(dst, deg);
    scan1_kernel<<<gScan, 256, 0, stream>>>(deg, bsum);
    scan2_kernel<<<1, 128, 0, stream>>>(bsum, gScan, row_start);
    scan3_kernel<<<gScan, 256, 0, stream>>>(deg, bsum, row_start, cursor);
    scatter_xcd_kernel<<<4096, 256, 0, stream>>>(src, dst, cursor, esrc);

    // ---- 3 SAGE layers ----
    const short* Xl[3]  = {Xbf, B0, B1};
    short* hpb[3]       = {B0, B1, B0};
    short* aggb[3]      = {B1, B2, B2};
    short* Yb[3]        = {B0, B1, B0};
    for (int l = 0; l < 3; ++l) {
        const short* X = Xl[l];
        gemm_mfma<4><<<gGemm, 256, 0, stream>>>(X, (const short*)nullptr,
            wp_p + l * 16384, bp[l], (unsigned short*)hpb[l], N_NODES, 1);
        aggregate_max_bf16<<<gAgg, 256, 0, stream>>>(
            (const unsigned int*)hpb[l], row_start, esrc, (unsigned int*)aggb[l]);
        const int act = (l == 0) ? 2 : 0;
        gemm_mfma<8><<<gGemm, 256, 0, stream>>>(X, aggb[l],
            wsn_p + l * 32768, bb[l], (unsigned short*)Yb[l], N_NODES, act);
        if (l == 1) {
            zero_kernel<<<1, 256, 0, stream>>>((float4*)stats, 64);
            bn_stats_kernel<<<512, 256, 0, stream>>>(
                (const unsigned short*)Yb[l], stats, N_NODES);
            bn_finalize_kernel<<<1, 128, 0, stream>>>(stats, gamma, beta, coef);
            bn_apply_bf16<<<(int)((n2 + 255) / 256), 256, 0, stream>>>(
                (unsigned int*)Yb[l], coef, n2);
        }
    }
    classifier_kernel<<<(N_NODES + 15) / 16, 256, 0, stream>>>(
        (const unsigned short*)B0, wc, bc, (float*)d_out, N_NODES);
}